// Round 1
// baseline (417.677 us; speedup 1.0000x reference)
//
#include <hip/hip_runtime.h>
#include <math.h>

#define EPSF 1e-8f

__device__ __forceinline__ int PADi(int i) { return i + (i >> 5); }

template<int NV>
__device__ __forceinline__ void block_sum_batch(float* vals, float* red, int tid) {
  const int lane = tid & 63, wid = tid >> 6;
#pragma unroll
  for (int i = 0; i < NV; ++i) {
    float v = vals[i];
#pragma unroll
    for (int d = 32; d >= 1; d >>= 1) v += __shfl_down(v, d, 64);
    if (lane == 0) red[wid * NV + i] = v;
  }
  __syncthreads();
#pragma unroll
  for (int i = 0; i < NV; ++i)
    vals[i] = red[i] + red[NV + i] + red[2 * NV + i] + red[3 * NV + i];
  __syncthreads();
}

// block-wide exclusive prefix of per-thread chunk sums
__device__ __forceinline__ float block_scan_excl(float cs, float* red, int tid) {
  const int lane = tid & 63, wid = tid >> 6;
  float s = cs;
#pragma unroll
  for (int d = 1; d < 64; d <<= 1) {
    float t = __shfl_up(s, d, 64);
    if (lane >= d) s += t;
  }
  if (lane == 63) red[wid] = s;
  __syncthreads();
  float woff = 0.f;
#pragma unroll
  for (int w = 0; w < 4; ++w) woff += (w < wid) ? red[w] : 0.f;
  __syncthreads();
  return woff + s - cs;
}

// in-place radix-4 DIF stage; 256 butterflies, output digit-reversed (we never reorder)
template<int LEN>
__device__ __forceinline__ void fft_stage(float* fr, float* fi,
                                          const float* twr, const float* twi, int tid) {
  constexpr int H = LEN >> 2;
  constexpr int ESTEP = 1024 / LEN;
  const int g = tid / H;
  const int j = tid & (H - 1);
  const int base = g * LEN + j;
  const int i0 = PADi(base), i1 = PADi(base + H), i2 = PADi(base + 2 * H), i3 = PADi(base + 3 * H);
  float a0r = fr[i0], a0i = fi[i0];
  float a1r = fr[i1], a1i = fi[i1];
  float a2r = fr[i2], a2i = fi[i2];
  float a3r = fr[i3], a3i = fi[i3];
  float t0r = a0r + a2r, t0i = a0i + a2i;
  float t1r = a0r - a2r, t1i = a0i - a2i;
  float t2r = a1r + a3r, t2i = a1i + a3i;
  float t3r = a1r - a3r, t3i = a1i - a3i;
  float y0r = t0r + t2r, y0i = t0i + t2i;
  float y1r = t1r + t3i, y1i = t1i - t3r;   // (t1 - i*t3)
  float y2r = t0r - t2r, y2i = t0i - t2i;
  float y3r = t1r - t3i, y3i = t1i + t3r;   // (t1 + i*t3)
  const int e1 = j * ESTEP;
  const int e2 = 2 * e1, e3 = 3 * e1;
  const float c1 = twr[PADi(e1)], s1 = twi[PADi(e1)];
  const float c2 = twr[PADi(e2)], s2 = twi[PADi(e2)];
  const float c3 = twr[PADi(e3)], s3 = twi[PADi(e3)];
  fr[i0] = y0r;                       fi[i0] = y0i;
  fr[i1] = y1r * c1 - y1i * s1;       fi[i1] = y1r * s1 + y1i * c1;
  fr[i2] = y2r * c2 - y2i * s2;       fi[i2] = y2r * s2 + y2i * c2;
  fr[i3] = y3r * c3 - y3i * s3;       fi[i3] = y3r * s3 + y3i * c3;
}

__global__ void __launch_bounds__(256)
sr_kernel(const float* __restrict__ x,
          const float* __restrict__ ln_w, const float* __restrict__ ln_b,
          const float* __restrict__ w1, const float* __restrict__ b1,
          const float* __restrict__ w2, const float* __restrict__ b2,
          float* __restrict__ out, int B)
{
  __shared__ float fr[1056], fi[1056], twr[1056], twi[1056];
  __shared__ float ps[1025];
  __shared__ float red[64];

  const int tid  = threadIdx.x;
  const int lane = tid & 63;
  const int wid  = tid >> 6;
  const int row  = blockIdx.x;
  if (row >= B) return;
  const float* __restrict__ xr = x + (size_t)row * 1024;

  // ---- load row + build twiddles ----
  const int c0 = tid * 4;
  const float4 v4 = *reinterpret_cast<const float4*>(xr + c0);
  fr[PADi(c0 + 0)] = v4.x; fr[PADi(c0 + 1)] = v4.y;
  fr[PADi(c0 + 2)] = v4.z; fr[PADi(c0 + 3)] = v4.w;
  fi[PADi(c0 + 0)] = 0.f; fi[PADi(c0 + 1)] = 0.f;
  fi[PADi(c0 + 2)] = 0.f; fi[PADi(c0 + 3)] = 0.f;
#pragma unroll
  for (int q = 0; q < 4; ++q) {
    int e = tid + q * 256;
    float sv, cv;
    sincosf(-6.283185307179586f * (float)e * (1.f / 1024.f), &sv, &cv);
    twr[PADi(e)] = cv; twi[PADi(e)] = sv;
  }
  __syncthreads();

  // ---- pre-FFT stats (x still pristine in fr) ----
  const float x0 = fr[PADi(0)];
  const float xl = fr[PADi(1023)];
  float vv[14];
  vv[0] = v4.x; vv[1] = v4.y; vv[2] = v4.z; vv[3] = v4.w;
#pragma unroll
  for (int j = 4; j < 14; ++j) {
    int idx = c0 + j;
    vv[j] = (idx < 1024) ? fr[PADi(idx)] : 0.f;
  }
  float vals[12];
  vals[0] = vv[0]*vv[0] + vv[1]*vv[1] + vv[2]*vv[2] + vv[3]*vv[3];  // sum x^2
  vals[1] = vv[0] - vv[1] + vv[2] - vv[3];                           // sum (-1)^n x  -> X[512]
#pragma unroll
  for (int k = 1; k <= 10; ++k) {
    float r = 0.f;
#pragma unroll
    for (int j = 0; j < 4; ++j) r += vv[j] * vv[j + k];              // zero-padded past end
    vals[1 + k] = r;                                                 // raw lag product R_k
  }
  // prefix sum of x -> ps[0..1024]
  const float cs4 = vv[0] + vv[1] + vv[2] + vv[3];
  const float excl = block_scan_excl(cs4, red, tid);
  ps[c0 + 1] = excl + vv[0];
  ps[c0 + 2] = excl + vv[0] + vv[1];
  ps[c0 + 3] = excl + vv[0] + vv[1] + vv[2];
  ps[c0 + 4] = excl + cs4;
  if (tid == 0) ps[0] = 0.f;
  block_sum_batch<12>(vals, red, tid);
  const float SUMSQ = vals[0];
  const float ALT   = vals[1];
  const float SUMX  = ps[1024];

  // ---- FFT (radix-4 DIF, in place, order-free) ----
  fft_stage<1024>(fr, fi, twr, twi, tid); __syncthreads();
  fft_stage<256>(fr, fi, twr, twi, tid);  __syncthreads();
  fft_stage<64>(fr, fi, twr, twi, tid);   __syncthreads();
  fft_stage<16>(fr, fi, twr, twi, tid);   __syncthreads();
  fft_stage<4>(fr, fi, twr, twi, tid);    __syncthreads();

  // ---- psd reductions over full spectrum ----
  float pq[4], psum = 0.f, pmax = 0.f;
#pragma unroll
  for (int q = 0; q < 4; ++q) {
    int p = tid + q * 256;
    float rr = fr[PADi(p)], ii = fi[PADi(p)];
    float pp = fmaxf(rr * rr + ii * ii, EPSF);
    pq[q] = pp; psum += pp; pmax = fmaxf(pmax, pp);
  }
#pragma unroll
  for (int d = 32; d >= 1; d >>= 1) {
    psum += __shfl_down(psum, d, 64);
    pmax = fmaxf(pmax, __shfl_down(pmax, d, 64));
  }
  if (lane == 0) { red[wid] = psum; red[4 + wid] = pmax; }
  __syncthreads();
  const float SFULL = red[0] + red[1] + red[2] + red[3];
  const float PMAX  = fmaxf(fmaxf(red[4], red[5]), fmaxf(red[6], red[7]));
  __syncthreads();
  const float p0b   = fmaxf(SUMX * SUMX, EPSF);   // |X[0]|^2 exactly
  const float p512b = fmaxf(ALT * ALT, EPSF);     // |X[512]|^2 exactly
  const float Sr    = 0.5f * (SFULL + p0b + p512b);   // rfft psd sum
  const float invS  = 1.f / Sr;
  float ts[1]; ts[0] = 0.f;
#pragma unroll
  for (int q = 0; q < 4; ++q) {
    float pn = pq[q] * invS;
    ts[0] += pn * __logf(pn + EPSF);
  }
  block_sum_batch<1>(ts, red, tid);
  const float g0   = (p0b * invS)   * __logf(p0b * invS + EPSF);
  const float g512 = (p512b * invS) * __logf(p512b * invS + EPSF);
  const float ent  = -0.5f * (ts[0] + g0 + g512);

  // ---- trend / kpss (all from prefix sums; no extra LDS passes) ----
  float trv[4], str = 0.f, str2 = 0.f;
#pragma unroll
  for (int j = 0; j < 4; ++j) {
    int i = c0 + j;
    int a = i - 12; a = a < 0 ? 0 : a;
    int b = i + 12; b = b > 1023 ? 1023 : b;
    float s = ps[b + 1] - ps[a];
    if (i < 12)   s += (float)(12 - i) * x0;
    if (i > 1011) s += (float)(i - 1011) * xl;
    float t = s * (1.f / 25.f);
    trv[j] = t; str += t; str2 += t * t;
  }
  const float texcl = block_scan_excl(trv[0] + trv[1] + trv[2] + trv[3], red, tid);
  float run = texcl, sc = 0.f, sc2 = 0.f;
#pragma unroll
  for (int j = 0; j < 4; ++j) {
    run += trv[j];
    float c = ps[c0 + j + 1] - run;   // cumsum(resid)[i]
    sc += c; sc2 += c * c;
  }
  float v4s[4] = {str, str2, sc, sc2};
  block_sum_batch<4>(v4s, red, tid);

  // ---- features ----
  const float m = SUMX * (1.f / 1024.f);
  const float den = SUMSQ - 1024.f * m * m + EPSF;
  const float invden = 1.f / den;
  float acf1 = 0.f, acf2 = 0.f, lbq = 0.f;
#pragma unroll
  for (int k = 1; k <= 10; ++k) {
    float num = vals[1 + k] - m * (ps[1024 - k] + (SUMX - ps[k])) + (float)(1024 - k) * m * m;
    float a = fminf(fmaxf(num * invden, -1.f), 1.f);
    if (k == 1) acf1 = a;
    else if (k == 2) acf2 = a;
    lbq += a * a;
  }
  const float spent = fminf(fmaxf(ent / (__logf(513.f + EPSF) + EPSF), 0.f), 1.f);
  const float peak  = fminf(fmaxf(PMAX / (Sr + EPSF), 0.f), 1.f);
  const float R1 = vals[2];
  const float phi = fminf(fmaxf(R1 / ((SUMSQ - xl * xl) + EPSF), -1.f), 1.f);
  const float invn = 1.f / 1023.f;
  const float sum_d2 = 2.f * SUMSQ - x0 * x0 - xl * xl - 2.f * R1;
  const float md = (xl - x0) * invn;
  const float diff_var = sum_d2 * invn - md * md;
  const float STR = v4s[0], STR2 = v4s[1], SC = v4s[2], SC2 = v4s[3];
  const float tstr = STR2 * (1.f / 1024.f) - (STR * (1.f / 1024.f)) * (STR * (1.f / 1024.f));
  const float varx = SUMSQ * (1.f / 1024.f) - m * m;
  const float mc = SC * (1.f / 1024.f);
  const float kpss = (SC2 * (1.f / 1024.f) - mc * mc) / (varx + 1e-8f);

  float f[9] = {acf1, acf2, spent, phi, diff_var, tstr, kpss, lbq, peak};
  float fm = 0.f;
#pragma unroll
  for (int d = 0; d < 9; ++d) fm += f[d];
  fm *= (1.f / 9.f);
  float fv = 0.f;
#pragma unroll
  for (int d = 0; d < 9; ++d) { float t = f[d] - fm; fv += t * t; }
  fv *= (1.f / 9.f);
  const float inl = 1.f / sqrtf(fv + 1e-5f);
  float fn[9];
#pragma unroll
  for (int d = 0; d < 9; ++d) fn[d] = (f[d] - fm) * inl * ln_w[d] + ln_b[d];

  if (tid == 0) {
#pragma unroll
    for (int d = 0; d < 9; ++d) red[d] = fn[d];
  }
  if (wid == 0) {
    float h = b1[lane];
#pragma unroll
    for (int d = 0; d < 9; ++d) h = fmaf(fn[d], w1[d * 64 + lane], h);
    h = fmaxf(h, 0.f);
    float l0 = h * w2[lane * 3 + 0];
    float l1 = h * w2[lane * 3 + 1];
    float l2 = h * w2[lane * 3 + 2];
#pragma unroll
    for (int d = 32; d >= 1; d >>= 1) {
      l0 += __shfl_down(l0, d, 64);
      l1 += __shfl_down(l1, d, 64);
      l2 += __shfl_down(l2, d, 64);
    }
    if (lane == 0) {
      l0 += b2[0]; l1 += b2[1]; l2 += b2[2];
      float mx = fmaxf(l0, fmaxf(l1, l2));
      float e0 = __expf(l0 - mx), e1 = __expf(l1 - mx), e2 = __expf(l2 - mx);
      float is = 1.f / (e0 + e1 + e2);
      float* o = out + (size_t)row * 3;
      o[0] = e0 * is; o[1] = e1 * is; o[2] = e2 * is;
    }
  }
  __syncthreads();
  if (tid < 9) out[(size_t)B * 3 + (size_t)row * 9 + tid] = red[tid];
}

extern "C" void kernel_launch(void* const* d_in, const int* in_sizes, int n_in,
                              void* d_out, int out_size, void* d_ws, size_t ws_size,
                              hipStream_t stream) {
  (void)n_in; (void)out_size; (void)d_ws; (void)ws_size;
  const float* x    = (const float*)d_in[0];
  const float* ln_w = (const float*)d_in[1];
  const float* ln_b = (const float*)d_in[2];
  const float* w1   = (const float*)d_in[3];
  const float* b1   = (const float*)d_in[4];
  const float* w2   = (const float*)d_in[5];
  const float* b2   = (const float*)d_in[6];
  float* out = (float*)d_out;
  const int B = in_sizes[0] / 1024;
  sr_kernel<<<B, 256, 0, stream>>>(x, ln_w, ln_b, w1, b1, w2, b2, out, B);
}